// Round 15
// baseline (220.578 us; speedup 1.0000x reference)
//
#include <hip/hip_runtime.h>
#include <hip/hip_bf16.h>

typedef unsigned short u16;
typedef unsigned int u32;
typedef __attribute__((ext_vector_type(8))) short short8;   // 8 bf16 (4 VGPRs)
typedef __attribute__((ext_vector_type(4))) float f32x4;    // MFMA accumulator
typedef __attribute__((ext_vector_type(4))) u16 u16x4;

static constexpr int Bb = 512, Tt = 256, Cc = 768, Hh = 64;

__device__ __forceinline__ u16 f2bf(float f) {
    __hip_bfloat16 h = __float2bfloat16(f);   // RNE
    union { __hip_bfloat16 h; u16 u; } v; v.h = h;
    return v.u;
}

__device__ __forceinline__ void gll16(const u16* g, u16* l) {
    __builtin_amdgcn_global_load_lds(
        (const __attribute__((address_space(1))) u32*)g,
        (__attribute__((address_space(3))) u32*)l, 16, 0, 0);
}

// ---------------------------------------------------------------------------
// Kernel 0: Wq|Wk|Wv -> per-K-chunk fragment-major image (proven):
//   chunk kc holds 24 frags of 1 KB: f = ksub*12 + nt; lane l of frag f gives
//   n = nt*16+(l&15), k = kc*64+ksub*32+(l>>4)*8+e.
// ---------------------------------------------------------------------------
__global__ void wt_kernel(const float* __restrict__ Wq, const float* __restrict__ Wk,
                          const float* __restrict__ Wv, u16* __restrict__ Wf) {
    int idx = blockIdx.x * 256 + threadIdx.x;          // 192*768
    int n = idx / Cc, k = idx % Cc;
    const float* W = (n < 64) ? Wq : (n < 128) ? Wk : Wv;
    float val = W[k * Hh + (n & 63)];
    int nt = n >> 4, fr = n & 15;
    int kc = k >> 6, ksub = (k >> 5) & 1, fk = k & 31;
    Wf[kc * 12288 + (ksub * 12 + nt) * 512 + (fr + ((fk >> 3) << 4)) * 8 + (fk & 7)] = f2bf(val);
}

// ---------------------------------------------------------------------------
// Fused kernel: PERSISTENT block over TWO batches (bid, bid+256); 512 thr.
// Identical to the r13 champion per batch, with ONE structural change: after
// batch A's GEMM main loop, batch B's first x chunk (8 loads) + W chunk
// (3 loads) are issued into registers; they complete under A's epilogue +
// phase-2 (~24k cy), so HBM never idles across the phase boundary and B's
// pipeline starts primed (also removes the inter-block launch gap).
// Per-batch: K-chunk rotation c0=b%12; XS dbuf + WS dbuf phase-1; LDS-bounce
// epilogue; per-wave causal attention phase-2.
// LDS map (bytes): phase1: XS dbuf [0,65536) | WS dbuf [65536,114688)
//                  phase2: KT [0,32768) | VT [32768,65536) | QB [65536,98304)
//                          P [98304,118784)
// ---------------------------------------------------------------------------
__global__ __launch_bounds__(512, 2) void fused_kernel(
        const float* __restrict__ x, const u16* __restrict__ Wf,
        const int* __restrict__ pad, float* __restrict__ out) {
    __shared__ u16 smem[59392];   // 118784 B
    char* smB = (char*)smem;

    const int tid = threadIdx.x;
    const int w = tid >> 6, l = tid & 63;
    const int lrow = l & 15, lgrp = l >> 4;
    const int cswz = (lrow & 7) << 4;
    const int tt0 = w, tt1 = 15 - w;          // owned query-row tiles

    float4 xr[8];
    short8 wr[3];
    f32x4 acc[2][12];

#define XLOAD(kc_)                                                             \
    _Pragma("unroll")                                                          \
    for (int j = 0; j < 8; ++j)                                                \
        xr[j] = *(const float4*)(xg + (size_t)j * 32 * Cc + (kc_) * 64);

#define XWRITE(nb_)                                                            \
    {                                                                          \
        char* xb_ = smB + (nb_) * 32768;                                       \
        _Pragma("unroll")                                                      \
        for (int j = 0; j < 8; ++j) {                                          \
            int row = j * 32 + (tid >> 4);                                     \
            u16x4 pk;                                                          \
            pk[0] = f2bf(xr[j].x); pk[1] = f2bf(xr[j].y);                      \
            pk[2] = f2bf(xr[j].z); pk[3] = f2bf(xr[j].w);                      \
            *(u16x4*)(xb_ + ((row * 128 + (tid & 15) * 8) ^ ((row & 7) << 4))) = pk; \
        }                                                                      \
    }

#define WSTAGE(kc_, nb_)                                                       \
    {                                                                          \
        u16* wl_ = smem + 32768 + (nb_) * 12288;                               \
        const u16* wg_ = Wf + (size_t)(kc_) * 12288;                           \
        _Pragma("unroll")                                                      \
        for (int p = 0; p < 3; ++p)                                            \
            gll16(wg_ + (p * 8 + w) * 512 + l * 8, wl_ + (p * 8 + w) * 512);   \
    }

#define COMPUTE(cur_)                                                          \
    {                                                                          \
        const char* xb = smB + (cur_) * 32768;                                 \
        const char* wb = smB + 65536 + (cur_) * 24576;                         \
        _Pragma("unroll")                                                      \
        for (int ksub = 0; ksub < 2; ++ksub) {                                 \
            short8 bfr[12], af[2];                                             \
            _Pragma("unroll")                                                  \
            for (int nt = 0; nt < 12; ++nt)                                    \
                bfr[nt] = *(const short8*)(wb + (ksub * 12 + nt) * 1024 + l * 16); \
            af[0] = *(const short8*)(xb +                                      \
                (((tt0 * 16 + lrow) * 128 + ksub * 64 + lgrp * 16) ^ cswz));   \
            af[1] = *(const short8*)(xb +                                      \
                (((tt1 * 16 + lrow) * 128 + ksub * 64 + lgrp * 16) ^ cswz));   \
            _Pragma("unroll")                                                  \
            for (int mrep = 0; mrep < 2; ++mrep)                               \
                _Pragma("unroll")                                              \
                for (int nt = 0; nt < 12; ++nt)                                \
                    acc[mrep][nt] = __builtin_amdgcn_mfma_f32_16x16x32_bf16(   \
                        af[mrep], bfr[nt], acc[mrep][nt], 0, 0, 0);            \
        }                                                                      \
    }

#pragma unroll 1
    for (int half = 0; half < 2; ++half) {
        const int b = blockIdx.x + half * 256;
        const int c0 = b % 12;                 // per-batch chunk rotation phase
        const float* xg = x + ((size_t)b * Tt + (tid >> 4)) * Cc + (tid & 15) * 4;

#pragma unroll
        for (int i = 0; i < 2; ++i)
#pragma unroll
            for (int j = 0; j < 12; ++j) acc[i][j] = (f32x4)0.f;

        // ---- Phase-1 prologue ----
        if (half == 0) {
            XLOAD(c0); WSTAGE(c0, 0); XWRITE(0);
        } else {
            __syncthreads();   // prev phase-2 LDS reads done before overwrite
            XWRITE(0);         // xr prefetched during prev phase-2 (chunk c0)
#pragma unroll
            for (int p = 0; p < 3; ++p)        // wr prefetched W chunk c0
                *(short8*)(smem + 32768 + (p * 8 + w) * 512 + l * 8) = wr[p];
        }
        __syncthreads();

        // ---- Main loop (rotated chunk order) ----
        int pn = c0;
#pragma unroll 1
        for (int kc = 0; kc < 12; ++kc) {
            const int cur = kc & 1;
            pn = (pn == 11) ? 0 : pn + 1;
            if (kc < 11) { WSTAGE(pn, cur ^ 1); XLOAD(pn); }
            COMPUTE(cur);
            if (kc < 11) { XWRITE(cur ^ 1); }
            __syncthreads();
        }

        // ---- Cross-phase prefetch: next batch's first chunk -> registers ---
        if (half == 0) {
            const int bn = blockIdx.x + 256;
            const int c0n = bn % 12;
            const float* xgn = x + ((size_t)bn * Tt + (tid >> 4)) * Cc + (tid & 15) * 4;
#pragma unroll
            for (int j = 0; j < 8; ++j)
                xr[j] = *(const float4*)(xgn + (size_t)j * 32 * Cc + c0n * 64);
#pragma unroll
            for (int p = 0; p < 3; ++p)
                wr[p] = *(const short8*)(Wf + (size_t)c0n * 12288 + (p * 8 + w) * 512 + l * 8);
            __builtin_amdgcn_sched_barrier(0);  // pin issue before phase-2
        }

        // ---- Epilogue: acc -> KT / VT / QB ----
#pragma unroll
        for (int mrep = 0; mrep < 2; ++mrep) {
            const int tt = (mrep == 0) ? tt0 : tt1;
            const int s0 = tt * 16;
#pragma unroll
            for (int nt = 0; nt < 12; ++nt) {
                f32x4 a = acc[mrep][nt];
                if (nt < 4) {                       // Q -> QB [256][64]
                    int h = nt * 16 + lrow;
#pragma unroll
                    for (int r = 0; r < 4; ++r) {
                        int row = s0 + lgrp * 4 + r;
                        *(u16*)(smB + 65536 + ((row * 128 + h * 2) ^ ((row & 7) << 4))) = f2bf(a[r]);
                    }
                } else if (nt < 8) {                // K -> KT [256][64]
                    int h = (nt - 4) * 16 + lrow;
#pragma unroll
                    for (int r = 0; r < 4; ++r) {
                        int s = s0 + lgrp * 4 + r;
                        *(u16*)(smB + ((s * 128 + h * 2) ^ ((s & 7) << 4))) = f2bf(a[r]);
                    }
                } else {                            // V -> VT [64][256]
                    int h = (nt - 8) * 16 + lrow;
                    int s = s0 + lgrp * 4;
                    u16x4 pk;
                    pk[0] = f2bf(a[0]); pk[1] = f2bf(a[1]);
                    pk[2] = f2bf(a[2]); pk[3] = f2bf(a[3]);
                    *(u16x4*)(smB + 32768 + h * 512 + ((s * 2) ^ ((h & 15) << 4))) = pk;
                }
            }
        }
        __syncthreads();

        // Q fragment readback
        short8 qfr[2][2];
#pragma unroll
        for (int mt = 0; mt < 2; ++mt) {
            const int tt = (mt == 0) ? tt0 : tt1;
#pragma unroll
            for (int kk = 0; kk < 2; ++kk)
                qfr[mt][kk] = *(const short8*)(smB + 65536 +
                    (((tt * 16 + lrow) * 128 + kk * 64 + lgrp * 16) ^ cswz));
        }
        __syncthreads();    // qfr reads done before P overwrites QB space

        // ---- Phase 2: causal attention (per-wave, no barriers) ----
        char* pbase = smB + 98304 + w * 2560;
#pragma unroll
        for (int mt = 0; mt < 2; ++mt) {
            const int tt = (mt == 0) ? tt0 : tt1;
            const int i0 = tt * 16;

            f32x4 sreg[16];
#pragma unroll
            for (int t = 0; t < 16; ++t) {
                if (t <= tt) {
                    short8 k0 = *(const short8*)(smB +
                        (((t * 16 + lrow) * 128 + lgrp * 16) ^ cswz));
                    short8 k1 = *(const short8*)(smB +
                        (((t * 16 + lrow) * 128 + 64 + lgrp * 16) ^ cswz));
                    f32x4 s = (f32x4)0.f;
                    s = __builtin_amdgcn_mfma_f32_16x16x32_bf16(qfr[mt][0], k0, s, 0, 0, 0);
                    s = __builtin_amdgcn_mfma_f32_16x16x32_bf16(qfr[mt][1], k1, s, 0, 0, 0);
                    if (t == tt) {
#pragma unroll
                        for (int r = 0; r < 4; ++r) {
                            int i = i0 + lgrp * 4 + r;
                            int sidx = t * 16 + lrow;
                            sreg[t][r] = (sidx <= i) ? s[r] * 0.125f : -1e30f;
                        }
                    } else {
#pragma unroll
                        for (int r = 0; r < 4; ++r) sreg[t][r] = s[r] * 0.125f;
                    }
                }
            }

            f32x4 mx = (f32x4)(-1e30f);
#pragma unroll
            for (int t = 0; t < 16; ++t)
                if (t <= tt)
#pragma unroll
                    for (int r = 0; r < 4; ++r) mx[r] = fmaxf(mx[r], sreg[t][r]);
#pragma unroll
            for (int m = 1; m <= 8; m <<= 1)
#pragma unroll
                for (int r = 0; r < 4; ++r) mx[r] = fmaxf(mx[r], __shfl_xor(mx[r], m, 64));

            f32x4 sm = (f32x4)0.f;
#pragma unroll
            for (int t = 0; t < 16; ++t)
                if (t <= tt)
#pragma unroll
                    for (int r = 0; r < 4; ++r) {
                        float p = __expf(sreg[t][r] - mx[r]);
                        sreg[t][r] = p;
                        sm[r] += p;
                    }
#pragma unroll
            for (int m = 1; m <= 8; m <<= 1)
#pragma unroll
                for (int r = 0; r < 4; ++r) sm[r] += __shfl_xor(sm[r], m, 64);

            float inv[4];
#pragma unroll
            for (int r = 0; r < 4; ++r) {
                int i = i0 + lgrp * 4 + r;
                inv[r] = (pad[b * Tt + i] != 0) ? (1.0f / sm[r]) : 0.0f;
            }

            f32x4 o[4];
#pragma unroll
            for (int ht = 0; ht < 4; ++ht) o[ht] = (f32x4)0.f;
#pragma unroll
            for (int ks = 0; ks < 8; ++ks) {
                if (2 * ks <= tt) {
                    char* pb = pbase + (ks & 1) * 1280;
#pragma unroll
                    for (int r = 0; r < 4; ++r) {
                        int prow = lgrp * 4 + r;
                        *(u16*)(pb + prow * 80 + lrow * 2) = f2bf(sreg[2 * ks][r]);
                        u16 pv2 = (2 * ks + 1 <= tt) ? f2bf(sreg[2 * ks + 1][r]) : (u16)0;
                        *(u16*)(pb + prow * 80 + 32 + lrow * 2) = pv2;
                    }
                    short8 pa = *(const short8*)(pb + lrow * 80 + lgrp * 16);
#pragma unroll
                    for (int ht = 0; ht < 4; ++ht) {
                        short8 vfr = *(const short8*)(smB + 32768 + (ht * 16 + lrow) * 512 +
                            ((ks * 64 + lgrp * 16) ^ (lrow << 4)));
                        o[ht] = __builtin_amdgcn_mfma_f32_16x16x32_bf16(pa, vfr, o[ht], 0, 0, 0);
                    }
                }
            }

            float* outp = out + ((size_t)b * Tt + i0) * Hh;
#pragma unroll
            for (int r = 0; r < 4; ++r)
#pragma unroll
                for (int ht = 0; ht < 4; ++ht)
                    outp[(lgrp * 4 + r) * Hh + ht * 16 + lrow] = o[ht][r] * inv[r];
        }
    }
#undef XLOAD
#undef XWRITE
#undef WSTAGE
#undef COMPUTE
}

// ---------------------------------------------------------------------------
extern "C" void kernel_launch(void* const* d_in, const int* in_sizes, int n_in,
                              void* d_out, int out_size, void* d_ws, size_t ws_size,
                              hipStream_t stream) {
    const float* x  = (const float*)d_in[0];
    const float* Wq = (const float*)d_in[1];
    const float* Wk = (const float*)d_in[2];
    const float* Wv = (const float*)d_in[3];
    const int* pad  = (const int*)d_in[4];
    float* out = (float*)d_out;

    u16* Wf = (u16*)d_ws;    // 294912 B

    wt_kernel<<<576, 256, 0, stream>>>(Wq, Wk, Wv, Wf);
    fused_kernel<<<256, 512, 0, stream>>>(x, Wf, pad, out);
}

// Round 16
// 120.114 us; speedup vs baseline: 1.8364x; 1.8364x over previous
//
#include <hip/hip_runtime.h>
#include <hip/hip_bf16.h>

typedef unsigned short u16;
typedef unsigned int u32;
typedef __attribute__((ext_vector_type(8))) short short8;   // 8 bf16 (4 VGPRs)
typedef __attribute__((ext_vector_type(4))) float f32x4;    // MFMA accumulator
typedef __attribute__((ext_vector_type(4))) u16 u16x4;

static constexpr int Bb = 512, Tt = 256, Cc = 768, Hh = 64;

__device__ __forceinline__ u16 f2bf(float f) {
    __hip_bfloat16 h = __float2bfloat16(f);   // RNE
    union { __hip_bfloat16 h; u16 u; } v; v.h = h;
    return v.u;
}

__device__ __forceinline__ void gll16(const u16* g, u16* l) {
    __builtin_amdgcn_global_load_lds(
        (const __attribute__((address_space(1))) u32*)g,
        (__attribute__((address_space(3))) u32*)l, 16, 0, 0);
}

// ---------------------------------------------------------------------------
// Kernel 0: Wq|Wk|Wv -> per-K-chunk fragment-major image (proven):
//   chunk kc holds 24 frags of 1 KB: f = ksub*12 + nt; lane l of frag f gives
//   n = nt*16+(l&15), k = kc*64+ksub*32+(l>>4)*8+e.
// ---------------------------------------------------------------------------
__global__ void wt_kernel(const float* __restrict__ Wq, const float* __restrict__ Wk,
                          const float* __restrict__ Wv, u16* __restrict__ Wf) {
    int idx = blockIdx.x * 256 + threadIdx.x;          // 192*768
    int n = idx / Cc, k = idx % Cc;
    const float* W = (n < 64) ? Wq : (n < 128) ? Wk : Wv;
    float val = W[k * Hh + (n & 63)];
    int nt = n >> 4, fr = n & 15;
    int kc = k >> 6, ksub = (k >> 5) & 1, fk = k & 31;
    Wf[kc * 12288 + (ksub * 12 + nt) * 512 + (fr + ((fk >> 3) << 4)) * 8 + (fk & 7)] = f2bf(val);
}

// ---------------------------------------------------------------------------
// Fused kernel: one block per batch. 512 thr = 8 waves.  r13 champion
// VERBATIM except the occupancy attribute: amdgpu_waves_per_eu(2,2) tells the
// allocator occupancy is LDS-capped at 2 waves/EU (1 block/CU), so it may use
// the full 256-VGPR budget instead of squeezing to 128 and spilling (r15
// showed VGPR_Count=128 with ~134 MB of scratch writes on this structure).
// LDS map (bytes): phase1: XS dbuf [0,65536) | WS dbuf [65536,114688)
//                  phase2: KT [0,32768) | VT [32768,65536) | QB [65536,98304)
//                          P [98304,118784)
// ---------------------------------------------------------------------------
__global__ __attribute__((amdgpu_flat_work_group_size(512, 512),
                          amdgpu_waves_per_eu(2, 2)))
void fused_kernel(
        const float* __restrict__ x, const u16* __restrict__ Wf,
        const int* __restrict__ pad, float* __restrict__ out) {
    __shared__ u16 smem[59392];   // 118784 B
    char* smB = (char*)smem;

    const int tid = threadIdx.x;
    const int w = tid >> 6, l = tid & 63;
    const int lrow = l & 15, lgrp = l >> 4;
    const int b = blockIdx.x;
    const int cswz = (lrow & 7) << 4;
    const int tt0 = w, tt1 = 15 - w;          // owned query-row tiles
    const int c0 = b % 12;                     // per-block chunk rotation phase

    const float* xg = x + ((size_t)b * Tt + (tid >> 4)) * Cc + (tid & 15) * 4;

    float4 xr[8];
    f32x4 acc[2][12];
#pragma unroll
    for (int i = 0; i < 2; ++i)
#pragma unroll
        for (int j = 0; j < 12; ++j) acc[i][j] = (f32x4)0.f;

#define XLOAD(kc_)                                                             \
    _Pragma("unroll")                                                          \
    for (int j = 0; j < 8; ++j)                                                \
        xr[j] = *(const float4*)(xg + (size_t)j * 32 * Cc + (kc_) * 64);

#define XWRITE(nb_)                                                            \
    {                                                                          \
        char* xb_ = smB + (nb_) * 32768;                                       \
        _Pragma("unroll")                                                      \
        for (int j = 0; j < 8; ++j) {                                          \
            int row = j * 32 + (tid >> 4);                                     \
            u16x4 pk;                                                          \
            pk[0] = f2bf(xr[j].x); pk[1] = f2bf(xr[j].y);                      \
            pk[2] = f2bf(xr[j].z); pk[3] = f2bf(xr[j].w);                      \
            *(u16x4*)(xb_ + ((row * 128 + (tid & 15) * 8) ^ ((row & 7) << 4))) = pk; \
        }                                                                      \
    }

#define WSTAGE(kc_, nb_)                                                       \
    {                                                                          \
        u16* wl_ = smem + 32768 + (nb_) * 12288;                               \
        const u16* wg_ = Wf + (size_t)(kc_) * 12288;                           \
        _Pragma("unroll")                                                      \
        for (int p = 0; p < 3; ++p)                                            \
            gll16(wg_ + (p * 8 + w) * 512 + l * 8, wl_ + (p * 8 + w) * 512);   \
    }

#define COMPUTE(cur_)                                                          \
    {                                                                          \
        const char* xb = smB + (cur_) * 32768;                                 \
        const char* wb = smB + 65536 + (cur_) * 24576;                         \
        _Pragma("unroll")                                                      \
        for (int ksub = 0; ksub < 2; ++ksub) {                                 \
            short8 bfr[12], af[2];                                             \
            _Pragma("unroll")                                                  \
            for (int nt = 0; nt < 12; ++nt)                                    \
                bfr[nt] = *(const short8*)(wb + (ksub * 12 + nt) * 1024 + l * 16); \
            af[0] = *(const short8*)(xb +                                      \
                (((tt0 * 16 + lrow) * 128 + ksub * 64 + lgrp * 16) ^ cswz));   \
            af[1] = *(const short8*)(xb +                                      \
                (((tt1 * 16 + lrow) * 128 + ksub * 64 + lgrp * 16) ^ cswz));   \
            _Pragma("unroll")                                                  \
            for (int mrep = 0; mrep < 2; ++mrep)                               \
                _Pragma("unroll")                                              \
                for (int nt = 0; nt < 12; ++nt)                                \
                    acc[mrep][nt] = __builtin_amdgcn_mfma_f32_16x16x32_bf16(   \
                        af[mrep], bfr[nt], acc[mrep][nt], 0, 0, 0);            \
        }                                                                      \
    }

    // ---- Phase 1 (rotated chunk order) ----
    XLOAD(c0); WSTAGE(c0, 0); XWRITE(0);
    __syncthreads();
    int pn = c0;                               // pn tracks (c0+kc+1)%12
    for (int kc = 0; kc < 12; ++kc) {
        const int cur = kc & 1;
        pn = (pn == 11) ? 0 : pn + 1;
        if (kc < 11) { WSTAGE(pn, cur ^ 1); XLOAD(pn); }
        COMPUTE(cur);
        if (kc < 11) { XWRITE(cur ^ 1); }
        __syncthreads();
    }
#undef XLOAD
#undef XWRITE
#undef WSTAGE
#undef COMPUTE

    // ---- Epilogue: acc -> KT / VT / QB ----
#pragma unroll
    for (int mrep = 0; mrep < 2; ++mrep) {
        const int tt = (mrep == 0) ? tt0 : tt1;
        const int s0 = tt * 16;
#pragma unroll
        for (int nt = 0; nt < 12; ++nt) {
            f32x4 a = acc[mrep][nt];
            if (nt < 4) {                       // Q -> QB [256][64]
                int h = nt * 16 + lrow;
#pragma unroll
                for (int r = 0; r < 4; ++r) {
                    int row = s0 + lgrp * 4 + r;
                    *(u16*)(smB + 65536 + ((row * 128 + h * 2) ^ ((row & 7) << 4))) = f2bf(a[r]);
                }
            } else if (nt < 8) {                // K -> KT [256][64]
                int h = (nt - 4) * 16 + lrow;
#pragma unroll
                for (int r = 0; r < 4; ++r) {
                    int s = s0 + lgrp * 4 + r;
                    *(u16*)(smB + ((s * 128 + h * 2) ^ ((s & 7) << 4))) = f2bf(a[r]);
                }
            } else {                            // V -> VT [64][256]
                int h = (nt - 8) * 16 + lrow;
                int s = s0 + lgrp * 4;
                u16x4 pk;
                pk[0] = f2bf(a[0]); pk[1] = f2bf(a[1]);
                pk[2] = f2bf(a[2]); pk[3] = f2bf(a[3]);
                *(u16x4*)(smB + 32768 + h * 512 + ((s * 2) ^ ((h & 15) << 4))) = pk;
            }
        }
    }
    __syncthreads();

    // Q fragment readback
    short8 qfr[2][2];
#pragma unroll
    for (int mt = 0; mt < 2; ++mt) {
        const int tt = (mt == 0) ? tt0 : tt1;
#pragma unroll
        for (int kk = 0; kk < 2; ++kk)
            qfr[mt][kk] = *(const short8*)(smB + 65536 +
                (((tt * 16 + lrow) * 128 + kk * 64 + lgrp * 16) ^ cswz));
    }
    __syncthreads();    // all qfr reads done before P overwrites QB space

    // ---- Phase 2: causal attention (per-wave, no barriers) ----
    char* pbase = smB + 98304 + w * 2560;
#pragma unroll
    for (int mt = 0; mt < 2; ++mt) {
        const int tt = (mt == 0) ? tt0 : tt1;
        const int i0 = tt * 16;

        f32x4 sreg[16];
#pragma unroll
        for (int t = 0; t < 16; ++t) {
            if (t <= tt) {
                short8 k0 = *(const short8*)(smB +
                    (((t * 16 + lrow) * 128 + lgrp * 16) ^ cswz));
                short8 k1 = *(const short8*)(smB +
                    (((t * 16 + lrow) * 128 + 64 + lgrp * 16) ^ cswz));
                f32x4 s = (f32x4)0.f;
                s = __builtin_amdgcn_mfma_f32_16x16x32_bf16(qfr[mt][0], k0, s, 0, 0, 0);
                s = __builtin_amdgcn_mfma_f32_16x16x32_bf16(qfr[mt][1], k1, s, 0, 0, 0);
                if (t == tt) {
#pragma unroll
                    for (int r = 0; r < 4; ++r) {
                        int i = i0 + lgrp * 4 + r;
                        int sidx = t * 16 + lrow;
                        sreg[t][r] = (sidx <= i) ? s[r] * 0.125f : -1e30f;
                    }
                } else {
#pragma unroll
                    for (int r = 0; r < 4; ++r) sreg[t][r] = s[r] * 0.125f;
                }
            }
        }

        f32x4 mx = (f32x4)(-1e30f);
#pragma unroll
        for (int t = 0; t < 16; ++t)
            if (t <= tt)
#pragma unroll
                for (int r = 0; r < 4; ++r) mx[r] = fmaxf(mx[r], sreg[t][r]);
#pragma unroll
        for (int m = 1; m <= 8; m <<= 1)
#pragma unroll
            for (int r = 0; r < 4; ++r) mx[r] = fmaxf(mx[r], __shfl_xor(mx[r], m, 64));

        f32x4 sm = (f32x4)0.f;
#pragma unroll
        for (int t = 0; t < 16; ++t)
            if (t <= tt)
#pragma unroll
                for (int r = 0; r < 4; ++r) {
                    float p = __expf(sreg[t][r] - mx[r]);
                    sreg[t][r] = p;
                    sm[r] += p;
                }
#pragma unroll
        for (int m = 1; m <= 8; m <<= 1)
#pragma unroll
            for (int r = 0; r < 4; ++r) sm[r] += __shfl_xor(sm[r], m, 64);

        float inv[4];
#pragma unroll
        for (int r = 0; r < 4; ++r) {
            int i = i0 + lgrp * 4 + r;
            inv[r] = (pad[b * Tt + i] != 0) ? (1.0f / sm[r]) : 0.0f;
        }

        f32x4 o[4];
#pragma unroll
        for (int ht = 0; ht < 4; ++ht) o[ht] = (f32x4)0.f;
#pragma unroll
        for (int ks = 0; ks < 8; ++ks) {
            if (2 * ks <= tt) {
                char* pb = pbase + (ks & 1) * 1280;
#pragma unroll
                for (int r = 0; r < 4; ++r) {
                    int prow = lgrp * 4 + r;
                    *(u16*)(pb + prow * 80 + lrow * 2) = f2bf(sreg[2 * ks][r]);
                    u16 pv2 = (2 * ks + 1 <= tt) ? f2bf(sreg[2 * ks + 1][r]) : (u16)0;
                    *(u16*)(pb + prow * 80 + 32 + lrow * 2) = pv2;
                }
                short8 pa = *(const short8*)(pb + lrow * 80 + lgrp * 16);
#pragma unroll
                for (int ht = 0; ht < 4; ++ht) {
                    short8 vfr = *(const short8*)(smB + 32768 + (ht * 16 + lrow) * 512 +
                        ((ks * 64 + lgrp * 16) ^ (lrow << 4)));
                    o[ht] = __builtin_amdgcn_mfma_f32_16x16x32_bf16(pa, vfr, o[ht], 0, 0, 0);
                }
            }
        }

        float* outp = out + ((size_t)b * Tt + i0) * Hh;
#pragma unroll
        for (int r = 0; r < 4; ++r)
#pragma unroll
            for (int ht = 0; ht < 4; ++ht)
                outp[(lgrp * 4 + r) * Hh + ht * 16 + lrow] = o[ht][r] * inv[r];
    }
}

// ---------------------------------------------------------------------------
extern "C" void kernel_launch(void* const* d_in, const int* in_sizes, int n_in,
                              void* d_out, int out_size, void* d_ws, size_t ws_size,
                              hipStream_t stream) {
    const float* x  = (const float*)d_in[0];
    const float* Wq = (const float*)d_in[1];
    const float* Wk = (const float*)d_in[2];
    const float* Wv = (const float*)d_in[3];
    const int* pad  = (const int*)d_in[4];
    float* out = (float*)d_out;

    u16* Wf = (u16*)d_ws;    // 294912 B

    wt_kernel<<<576, 256, 0, stream>>>(Wq, Wk, Wv, Wf);
    fused_kernel<<<Bb, 512, 0, stream>>>(x, Wf, pad, out);
}